// Round 1
// baseline (764.077 us; speedup 1.0000x reference)
//
#include <hip/hip_runtime.h>
#include <hip/hip_bf16.h>
#include <stdint.h>

#define BATCH 8192
#define VOCAB 16384
#define EMBED 256

#define BM 64
#define BK 64
#define KSPLIT 4
#define KRANGE (VOCAB / KSPLIT)   // 4096
#define KITERS (KRANGE / BK)      // 64
#define MTILES (BATCH / BM)       // 128

typedef __attribute__((ext_vector_type(4))) float    f32x4;
typedef __attribute__((ext_vector_type(4))) int      i32x4;
typedef __attribute__((ext_vector_type(4))) unsigned u32x4;

#define EMB_WS_BYTES ((size_t)VOCAB * EMBED * 2)   // 8 MiB of bf16, swizzled K-tiles

__device__ __forceinline__ void gload_lds16(const void* g, void* l) {
    __builtin_amdgcn_global_load_lds(
        (const __attribute__((address_space(1))) unsigned int*)(uintptr_t)g,
        (__attribute__((address_space(3))) unsigned int*)(uint32_t)(uintptr_t)l,
        16, 0, 0);
}

__device__ __forceinline__ void mfma_bf16(f32x4& acc, i32x4 a, i32x4 b) {
    // D = A(16x32 bf16) * B(32x16 bf16) + D, fp32 acc. Inline asm avoids the
    // builtin operand-type (short8 vs __bf16x8) ambiguity; deps via "+v"/"v".
    asm("v_mfma_f32_16x16x32_bf16 %0, %1, %2, %0" : "+v"(acc) : "v"(a), "v"(b));
}

// ---------------------------------------------------------------------------
// prep: zero d_out; emb fp32 [16384][256] -> bf16 K-tiles [kt][256e][64k]
// with XOR swizzle baked in: byte(e,kk) = e*128 + ((kk*2) ^ ((e&7)<<4)).
// Main kernel then stages B with purely linear global_load_lds.
// ---------------------------------------------------------------------------
__global__ __launch_bounds__(256) void prep_kernel(
    const float* __restrict__ emb, unsigned short* __restrict__ emb_ws,
    float* __restrict__ out)
{
    int t = blockIdx.x * 256 + threadIdx.x;          // 0 .. 524287
    ((f32x4*)out)[t] = (f32x4){0.f, 0.f, 0.f, 0.f};  // zero 2M floats (atomic dst)

    int ko = t >> 8;          // k-oct 0..2047 (8 consecutive k)
    int e  = t & 255;
    union { unsigned short s[8]; u32x4 q; } v;
    #pragma unroll
    for (int j = 0; j < 8; ++j) {                    // coalesced across lanes (e)
        float f = emb[(size_t)(ko * 8 + j) * EMBED + e];
        unsigned u = __float_as_uint(f);
        u += 0x7FFFu + ((u >> 16) & 1u);             // RNE to bf16
        v.s[j] = (unsigned short)(u >> 16);
    }
    int kt  = ko >> 3;
    int kk0 = (ko & 7) * 8;
    unsigned byt = (unsigned)(e * 128 + ((kk0 * 2) ^ ((e & 7) << 4)));
    *(u32x4*)((char*)emb_ws + (size_t)kt * 32768 + byt) = v.q;
}

// ---------------------------------------------------------------------------
// gemm: C += mask_tile(bf16) @ embT_tile(bf16), split-K atomics into d_out.
// Per-row nonzero counts fused into A staging (x is read exactly once).
// ---------------------------------------------------------------------------
__global__ __launch_bounds__(256) void gemm_kernel(
    const int* __restrict__ x, const unsigned short* __restrict__ emb_ws,
    float* __restrict__ out, int* __restrict__ cnt_ws)
{
    __shared__ __align__(16) unsigned short As[BM * BK];     // 8 KB, swizzled
    __shared__ __align__(16) unsigned short Bs[EMBED * BK];  // 32 KB, swizzled

    int bid   = blockIdx.x;
    int mt    = bid & (MTILES - 1);   // consecutive bids share the split's B panel
    int split = bid >> 7;

    int tid  = threadIdx.x;
    int lane = tid & 63;
    int wave = tid >> 6;              // e-range = wave*64

    int ar = tid >> 2;                // A staging: 4 threads per row
    int aq = tid & 3;
    const int*  aptr  = x + (size_t)(mt * BM + ar) * VOCAB + split * KRANGE + aq * 4;
    const char* bbase = (const char*)emb_ws + (size_t)split * KITERS * 32768;

    int cnt = 0;
    f32x4 acc[4][4];
    #pragma unroll
    for (int i = 0; i < 4; ++i)
        #pragma unroll
        for (int j = 0; j < 4; ++j) acc[i][j] = (f32x4){0.f, 0.f, 0.f, 0.f};

    for (int kt = 0; kt < KITERS; ++kt) {
        // ---- stage B: linear async copy of the pre-swizzled 32 KB tile ----
        const char* bsrc = bbase + (size_t)kt * 32768 + tid * 16;
        #pragma unroll
        for (int i = 0; i < 8; ++i)
            gload_lds16(bsrc + i * 4096, (char*)Bs + tid * 16 + i * 4096);

        // ---- stage A: int4 loads (64B/4-lane coalesced), 0/1 -> bf16 bits ----
        const int* ap = aptr + kt * BK;
        i32x4 av[4];
        #pragma unroll
        for (int j = 0; j < 4; ++j) av[j] = *(const i32x4*)(ap + j * 16);

        #pragma unroll
        for (int j = 0; j < 4; ++j) {
            unsigned lo = (av[j].x ? 0x3F80u : 0u) | (av[j].y ? 0x3F800000u : 0u);
            unsigned hi = (av[j].z ? 0x3F80u : 0u) | (av[j].w ? 0x3F800000u : 0u);
            cnt += (av[j].x != 0) + (av[j].y != 0) + (av[j].z != 0) + (av[j].w != 0);
            int kk = aq * 4 + j * 16;
            unsigned byt = (unsigned)(ar * 128 + ((kk * 2) ^ ((ar & 7) << 4)));
            *(uint2*)((char*)As + byt) = make_uint2(lo, hi);
        }

        __syncthreads();   // compiler drains vmcnt (gload_lds) + lgkm before barrier

        #pragma unroll
        for (int ks = 0; ks < 2; ++ks) {
            int kg = ks * 32 + (lane >> 4) * 8;   // lane's k-start (A/B frag: k=8*(l>>4)+j)
            i32x4 af[4], bf[4];
            #pragma unroll
            for (int fm = 0; fm < 4; ++fm) {
                int row = fm * 16 + (lane & 15);
                af[fm] = *(const i32x4*)((const char*)As + row * 128 +
                                         ((kg * 2) ^ ((row & 7) << 4)));
            }
            #pragma unroll
            for (int fe = 0; fe < 4; ++fe) {
                int e = wave * 64 + fe * 16 + (lane & 15);
                bf[fe] = *(const i32x4*)((const char*)Bs + e * 128 +
                                         ((kg * 2) ^ ((e & 7) << 4)));
            }
            #pragma unroll
            for (int fm = 0; fm < 4; ++fm)
                #pragma unroll
                for (int fe = 0; fe < 4; ++fe)
                    mfma_bf16(acc[fm][fe], af[fm], bf[fe]);
        }
        __syncthreads();
    }

    // ---- per-row nonzero count: reduce the 4 threads of each row ----
    cnt += __shfl_xor(cnt, 1);
    cnt += __shfl_xor(cnt, 2);
    if (aq == 0) cnt_ws[split * BATCH + mt * BM + ar] = cnt;

    // MFMA->VALU/VMEM read hazard fence (inline-asm MFMA: compiler won't insert)
    #pragma unroll
    for (int fm = 0; fm < 4; ++fm)
        #pragma unroll
        for (int fe = 0; fe < 4; ++fe)
            asm volatile("s_nop 7\n\ts_nop 7" : "+v"(acc[fm][fe]));

    // ---- split-K accumulate: C/D layout col=lane&15, row=4*(lane>>4)+r ----
    #pragma unroll
    for (int fm = 0; fm < 4; ++fm) {
        int row = mt * BM + fm * 16 + (lane >> 4) * 4;
        #pragma unroll
        for (int fe = 0; fe < 4; ++fe) {
            int col = wave * 64 + fe * 16 + (lane & 15);
            float* p = out + (size_t)row * EMBED + col;
            #pragma unroll
            for (int r = 0; r < 4; ++r)
                atomicAdd(p + (size_t)r * EMBED, acc[fm][fe][r]);
        }
    }
}

__global__ __launch_bounds__(256) void div_kernel(
    float* __restrict__ out, const int* __restrict__ cnt_ws)
{
    int t = blockIdx.x * 256 + threadIdx.x;   // float4 index
    int b = t >> 6;                           // 64 float4 per row
    float c = (float)(cnt_ws[b] + cnt_ws[BATCH + b] +
                      cnt_ws[2 * BATCH + b] + cnt_ws[3 * BATCH + b]);
    float inv = 1.0f / (c + 1e-6f);
    f32x4 v = ((f32x4*)out)[t];
    v.x *= inv; v.y *= inv; v.z *= inv; v.w *= inv;
    ((f32x4*)out)[t] = v;
}

extern "C" void kernel_launch(void* const* d_in, const int* in_sizes, int n_in,
                              void* d_out, int out_size, void* d_ws, size_t ws_size,
                              hipStream_t stream)
{
    const int*   x   = (const int*)d_in[0];
    const float* emb = (const float*)d_in[1];
    float*       out = (float*)d_out;

    unsigned short* emb_ws = (unsigned short*)d_ws;                 // 8 MiB
    int*            cnt_ws = (int*)((char*)d_ws + EMB_WS_BYTES);    // 128 KB

    prep_kernel<<<2048, 256, 0, stream>>>(emb, emb_ws, out);
    gemm_kernel<<<MTILES * KSPLIT, 256, 0, stream>>>(x, emb_ws, out, cnt_ws);
    div_kernel<<<2048, 256, 0, stream>>>(out, cnt_ws);
}

// Round 3
// 747.440 us; speedup vs baseline: 1.0223x; 1.0223x over previous
//
#include <hip/hip_runtime.h>
#include <hip/hip_bf16.h>
#include <stdint.h>

#define BATCH 8192
#define VOCAB 16384
#define EMBED 256

#define BM 64
#define BK 64
#define KSPLIT 8
#define KRANGE (VOCAB / KSPLIT)   // 2048
#define KITERS (KRANGE / BK)      // 32
#define MTILES (BATCH / BM)       // 128

typedef __attribute__((ext_vector_type(4))) float    f32x4;
typedef __attribute__((ext_vector_type(4))) int      i32x4;
typedef __attribute__((ext_vector_type(4))) unsigned u32x4;

#define EMB_WS_BYTES ((size_t)VOCAB * EMBED * 2)           // 8 MiB bf16, swizzled K-tiles
#define CNT_WS_BYTES ((size_t)KSPLIT * BATCH * 4)          // 256 KiB
#define PART_STRIDE  ((size_t)BATCH * EMBED)               // floats per split partial

__device__ __forceinline__ void gload_lds16(const void* g, void* l) {
    __builtin_amdgcn_global_load_lds(
        (const __attribute__((address_space(1))) unsigned int*)(uintptr_t)g,
        (__attribute__((address_space(3))) unsigned int*)(uint32_t)(uintptr_t)l,
        16, 0, 0);
}

__device__ __forceinline__ void mfma_bf16(f32x4& acc, i32x4 a, i32x4 b) {
    asm("v_mfma_f32_16x16x32_bf16 %0, %1, %2, %0" : "+v"(acc) : "v"(a), "v"(b));
}

// ---------------------------------------------------------------------------
// prep: emb fp32 [16384][256] -> bf16 K-tiles [kt][256e][64k] with the XOR
// swizzle baked in: byte(e,kk) = e*128 + ((kk*2) ^ ((e&7)<<4)). Main kernel
// stages B with purely linear global_load_lds (rule #21: pre-swizzled source).
// ---------------------------------------------------------------------------
__global__ __launch_bounds__(256) void prep_kernel(
    const float* __restrict__ emb, unsigned short* __restrict__ emb_ws)
{
    int t = blockIdx.x * 256 + threadIdx.x;          // 0 .. 524287
    int ko = t >> 8;          // k-oct 0..2047 (8 consecutive k)
    int e  = t & 255;
    union { unsigned short s[8]; u32x4 q; } v;
    #pragma unroll
    for (int j = 0; j < 8; ++j) {                    // coalesced across lanes (e)
        float f = emb[(size_t)(ko * 8 + j) * EMBED + e];
        unsigned u = __float_as_uint(f);
        u += 0x7FFFu + ((u >> 16) & 1u);             // RNE to bf16
        v.s[j] = (unsigned short)(u >> 16);
    }
    int kt  = ko >> 3;
    int kk0 = (ko & 7) * 8;
    unsigned byt = (unsigned)(e * 128 + ((kk0 * 2) ^ ((e & 7) << 4)));
    *(u32x4*)((char*)emb_ws + (size_t)kt * 32768 + byt) = v.q;
}

// ---------------------------------------------------------------------------
// gemm: partial[split] = mask_tile(bf16) @ embT_tile(bf16). Plain stores, no
// atomics. split = bid & 7  -> each XCD owns one split (B panel L2-resident,
// private 64 MiB x-column slab). Per-row nonzero counts fused into A staging.
// ---------------------------------------------------------------------------
__global__ __launch_bounds__(256, 4) void gemm_kernel(
    const int* __restrict__ x, const unsigned short* __restrict__ emb_ws,
    float* __restrict__ part_ws, int* __restrict__ cnt_ws)
{
    __shared__ __align__(16) unsigned short As[BM * BK];     // 8 KB, swizzled
    __shared__ __align__(16) unsigned short Bs[EMBED * BK];  // 32 KB, swizzled

    int bid   = blockIdx.x;
    int split = bid & (KSPLIT - 1);   // XCD affinity: bid%8 ~ XCD id
    int mt    = bid >> 3;

    int tid  = threadIdx.x;
    int lane = tid & 63;
    int wave = tid >> 6;              // e-range = wave*64

    int ar = tid >> 2;                // A staging: 4 threads per row
    int aq = tid & 3;
    const int*  aptr  = x + (size_t)(mt * BM + ar) * VOCAB + split * KRANGE + aq * 4;
    const char* bbase = (const char*)emb_ws + (size_t)split * KITERS * 32768;

    int cnt = 0;
    f32x4 acc[4][4];
    #pragma unroll
    for (int i = 0; i < 4; ++i)
        #pragma unroll
        for (int j = 0; j < 4; ++j) acc[i][j] = (f32x4){0.f, 0.f, 0.f, 0.f};

    for (int kt = 0; kt < KITERS; ++kt) {
        // ---- stage B: linear async copy of the pre-swizzled 32 KB tile ----
        const char* bsrc = bbase + (size_t)kt * 32768 + tid * 16;
        #pragma unroll
        for (int i = 0; i < 8; ++i)
            gload_lds16(bsrc + i * 4096, (char*)Bs + tid * 16 + i * 4096);

        // ---- stage A: int4 loads (64B/4-lane coalesced), 0/1 -> bf16 bits ----
        const int* ap = aptr + kt * BK;
        i32x4 av[4];
        #pragma unroll
        for (int j = 0; j < 4; ++j) av[j] = *(const i32x4*)(ap + j * 16);

        #pragma unroll
        for (int j = 0; j < 4; ++j) {
            unsigned lo = (av[j].x ? 0x3F80u : 0u) | (av[j].y ? 0x3F800000u : 0u);
            unsigned hi = (av[j].z ? 0x3F80u : 0u) | (av[j].w ? 0x3F800000u : 0u);
            cnt += (av[j].x != 0) + (av[j].y != 0) + (av[j].z != 0) + (av[j].w != 0);
            int kk = aq * 4 + j * 16;
            unsigned byt = (unsigned)(ar * 128 + ((kk * 2) ^ ((ar & 7) << 4)));
            *(uint2*)((char*)As + byt) = make_uint2(lo, hi);
        }

        __syncthreads();   // compiler drains vmcnt (gload_lds) + lgkm here

        #pragma unroll
        for (int ks = 0; ks < 2; ++ks) {
            int kg = ks * 32 + (lane >> 4) * 8;   // lane's k-start (frag k=8*(l>>4)+j)
            i32x4 af[4], bf[4];
            #pragma unroll
            for (int fm = 0; fm < 4; ++fm) {
                int row = fm * 16 + (lane & 15);
                af[fm] = *(const i32x4*)((const char*)As + row * 128 +
                                         ((kg * 2) ^ ((row & 7) << 4)));
            }
            #pragma unroll
            for (int fe = 0; fe < 4; ++fe) {
                int e = wave * 64 + fe * 16 + (lane & 15);
                bf[fe] = *(const i32x4*)((const char*)Bs + e * 128 +
                                         ((kg * 2) ^ ((e & 7) << 4)));
            }
            #pragma unroll
            for (int fm = 0; fm < 4; ++fm)
                #pragma unroll
                for (int fe = 0; fe < 4; ++fe)
                    mfma_bf16(acc[fm][fe], af[fm], bf[fe]);
        }
        __syncthreads();
    }

    // ---- per-row nonzero count: reduce the 4 threads of each row ----
    cnt += __shfl_xor(cnt, 1);
    cnt += __shfl_xor(cnt, 2);
    if (aq == 0) cnt_ws[split * BATCH + mt * BM + ar] = cnt;

    // MFMA->VALU/VMEM read hazard fence (inline-asm MFMA: compiler won't insert)
    #pragma unroll
    for (int fm = 0; fm < 4; ++fm)
        #pragma unroll
        for (int fe = 0; fe < 4; ++fe)
            asm volatile("s_nop 7\n\ts_nop 7" : "+v"(acc[fm][fe]));

    // ---- plain stores to this split's partial: C/D layout col=lane&15,
    //      row=4*(lane>>4)+r ----
    float* part = part_ws + (size_t)split * PART_STRIDE;
    #pragma unroll
    for (int fm = 0; fm < 4; ++fm) {
        int row = mt * BM + fm * 16 + (lane >> 4) * 4;
        #pragma unroll
        for (int fe = 0; fe < 4; ++fe) {
            int col = wave * 64 + fe * 16 + (lane & 15);
            float* p = part + (size_t)row * EMBED + col;
            #pragma unroll
            for (int r = 0; r < 4; ++r)
                p[(size_t)r * EMBED] = acc[fm][fe][r];
        }
    }
}

// ---------------------------------------------------------------------------
// div: out = (sum_s partial[s]) / (sum_s cnt[s] + eps)
// ---------------------------------------------------------------------------
__global__ __launch_bounds__(256) void div_kernel(
    float* __restrict__ out, const float* __restrict__ part_ws,
    const int* __restrict__ cnt_ws)
{
    int t = blockIdx.x * 256 + threadIdx.x;   // float4 index, 524288 total
    int b = t >> 6;                           // 64 float4 per row
    int c = 0;
    #pragma unroll
    for (int s = 0; s < KSPLIT; ++s) c += cnt_ws[s * BATCH + b];
    float inv = 1.0f / ((float)c + 1e-6f);
    f32x4 v = (f32x4){0.f, 0.f, 0.f, 0.f};
    #pragma unroll
    for (int s = 0; s < KSPLIT; ++s) {
        f32x4 p = ((const f32x4*)(part_ws + s * PART_STRIDE))[t];
        v.x += p.x; v.y += p.y; v.z += p.z; v.w += p.w;
    }
    v.x *= inv; v.y *= inv; v.z *= inv; v.w *= inv;
    ((f32x4*)out)[t] = v;
}

extern "C" void kernel_launch(void* const* d_in, const int* in_sizes, int n_in,
                              void* d_out, int out_size, void* d_ws, size_t ws_size,
                              hipStream_t stream)
{
    const int*   x   = (const int*)d_in[0];
    const float* emb = (const float*)d_in[1];
    float*       out = (float*)d_out;

    unsigned short* emb_ws  = (unsigned short*)d_ws;                        // 8 MiB
    int*            cnt_ws  = (int*)((char*)d_ws + EMB_WS_BYTES);           // 256 KiB
    float*          part_ws = (float*)((char*)d_ws + EMB_WS_BYTES + CNT_WS_BYTES); // 64 MiB

    prep_kernel<<<2048, 256, 0, stream>>>(emb, emb_ws);
    gemm_kernel<<<MTILES * KSPLIT, 256, 0, stream>>>(x, emb_ws, part_ws, cnt_ws);
    div_kernel<<<2048, 256, 0, stream>>>(out, part_ws, cnt_ws);
}